// Round 10
// baseline (165.144 us; speedup 1.0000x reference)
//
#include <hip/hip_runtime.h>
#include <hip/hip_bf16.h>

constexpr int T   = 16384;  // tokens
constexpr int HD  = 4096;   // hidden dim
constexpr int E   = 64;     // experts
constexpr int BKC = 32;     // k per chunk
constexpr int CPW = 32;     // chunks per wave (K-slice = 32*32 = 1024)

using short8 = __attribute__((ext_vector_type(8))) short;
using f32x4  = __attribute__((ext_vector_type(4))) float;

__device__ __forceinline__ unsigned short f2bf(float x) {
  union { float f; unsigned u; } v; v.f = x;
  return (unsigned short)((v.u + 0x7FFFu + ((v.u >> 16) & 1u)) >> 16);
}
__device__ __forceinline__ float bf2f(unsigned short h) {
  union { float f; unsigned u; } v; v.u = ((unsigned)h) << 16;
  return v.f;
}

// ---------------------------------------------------------------------------
// Kernel 0: pack W (fp32 [64][4096]) into bf16 hi/lo image:
// img[chunk 128][expert 64][slot 8] x 16B; slot 0..3 = hi k-group (8 bf16 of
// k [8s..8s+8)), slot 4..7 = lo residual of group s-4.
// ---------------------------------------------------------------------------
__global__ __launch_bounds__(256) void wprep(const float* __restrict__ W,
                                             short* __restrict__ img) {
  const int tid = blockIdx.x * 256 + threadIdx.x;   // 0..65535
  const int c   = tid >> 9;
  const int rem = tid & 511;
  const int e   = rem >> 3;
  const int sp  = rem & 7;
  const int part = sp >> 2;   // 0 = hi, 1 = lo
  const int sl   = sp & 3;    // k-group
  const float* src = W + (size_t)e * HD + c * BKC + sl * 8;
  short8 v;
#pragma unroll
  for (int j = 0; j < 8; ++j) {
    float x = src[j];
    unsigned short h = f2bf(x);
    v[j] = part ? (short)f2bf(x - bf2f(h)) : (short)h;
  }
  *(short8*)(img + (size_t)tid * 8) = v;
}

// ---------------------------------------------------------------------------
// Kernel 1: fused router — streaming/churn design, anti-sink enforced.
// 512 blocks x 512 threads (8 waves). Block = 32 rows x full K.
// Wave w: row-frag f=w&1 (16 rows), K-slice s=w>>1 (1024 k = 32 chunks).
// A: global->VGPR depth-3. B: single-slot, loaded at end of previous body
// (L2-resident image; compiler's vmcnt(2) before MFMA leaves A in flight).
// amdgpu_waves_per_eu(4,4): scheduler targets EXACTLY 128 VGPR — no sinking
// to chase occupancy. sched_barrier(0) per body: loads cannot sink across.
// Epilogue: 32 KB LDS reduction over 4 K-slices + logits + fused top-2.
// ---------------------------------------------------------------------------
__global__ __launch_bounds__(512)
__attribute__((amdgpu_waves_per_eu(4, 4)))
void router_fused(
    const float* __restrict__ H, const short* __restrict__ img,
    float* __restrict__ logits, float* __restrict__ topw, float* __restrict__ topi) {
  __shared__ __align__(16) float part[8][16][64];   // 32 KB

  const int tid  = threadIdx.x;
  const int w    = tid >> 6;
  const int lane = tid & 63;
  const int q    = lane >> 4;     // k-group / C row-group
  const int r    = lane & 15;     // A row / B expert sub-index
  const int fr   = w & 1;         // row-frag
  const int ks   = w >> 1;        // K-slice
  const int row0 = blockIdx.x * 32;

  const float* pA = H + (size_t)(row0 + 16 * fr + r) * HD + ks * 1024 + q * 8;
  const short* pB = img + (size_t)(ks * CPW) * 4096 + r * 64 + q * 8;

  f32x4  A[3][2];           // depth-3 A prefetch
  short8 Bh[4], Bl[4];      // single-slot B (4 col-tiles x hi/lo)
  f32x4  acc[4];
#pragma unroll
  for (int ct = 0; ct < 4; ++ct)
#pragma unroll
    for (int i = 0; i < 4; ++i) acc[ct][i] = 0.f;

  auto loadA = [&](int t, int sl) {
    A[sl][0] = *(const f32x4*)(pA + t * BKC);
    A[sl][1] = *(const f32x4*)(pA + t * BKC + 4);
  };
  auto loadB = [&](int t) {
    const short* p = pB + (size_t)t * 4096;
#pragma unroll
    for (int ct = 0; ct < 4; ++ct) {
      Bh[ct] = *(const short8*)(p + ct * 1024);
      Bl[ct] = *(const short8*)(p + ct * 1024 + 32);
    }
  };

  // HW packed f32->bf16 split: hi = rne(x,y), lo = rne(residual)
  auto cvtpk = [&](float x, float y, unsigned& hw, unsigned& lw) {
    union { __hip_bfloat162 b; unsigned u; } Hh, Ll;
    Hh.b = __float22bfloat162_rn(float2{x, y});
    float2 hf = __bfloat1622float2(Hh.b);
    Ll.b = __float22bfloat162_rn(float2{x - hf.x, y - hf.y});
    hw = Hh.u; lw = Ll.u;
  };

  // prologue
  loadA(0, 0);
  loadB(0);
  loadA(1, 1);
  loadA(2, 2);

#pragma unroll
  for (int t = 0; t < CPW; ++t) {
    const int sl = t % 3;
    union { short8 v; unsigned u[4]; } AH, AL;
    cvtpk(A[sl][0][0], A[sl][0][1], AH.u[0], AL.u[0]);
    cvtpk(A[sl][0][2], A[sl][0][3], AH.u[1], AL.u[1]);
    cvtpk(A[sl][1][0], A[sl][1][1], AH.u[2], AL.u[2]);
    cvtpk(A[sl][1][2], A[sl][1][3], AH.u[3], AL.u[3]);
    if (t + 3 < CPW) loadA(t + 3, (t + 3) % 3);   // same slot as just consumed
#pragma unroll
    for (int ct = 0; ct < 4; ++ct) {
      acc[ct] = __builtin_amdgcn_mfma_f32_16x16x32_bf16(AH.v, Bh[ct], acc[ct], 0, 0, 0);
      acc[ct] = __builtin_amdgcn_mfma_f32_16x16x32_bf16(AL.v, Bh[ct], acc[ct], 0, 0, 0);
      acc[ct] = __builtin_amdgcn_mfma_f32_16x16x32_bf16(AH.v, Bl[ct], acc[ct], 0, 0, 0);
    }
    if (t + 1 < CPW) loadB(t + 1);   // after MFMAs (WAR-safe via in-order issue)
    __builtin_amdgcn_sched_barrier(0);   // seal the body: no cross-body sinking
  }

  // --- store K-partials: D layout col = r (expert), row = 4q+rr ---
#pragma unroll
  for (int ct = 0; ct < 4; ++ct)
#pragma unroll
    for (int rr = 0; rr < 4; ++rr)
      part[w][4 * q + rr][16 * ct + r] = acc[ct][rr];
  __syncthreads();

  // --- reduce 4 K-slices: thread tid owns 4 floats (row tid>>4, col (tid&15)*4)
  {
    const int row = tid >> 4, col = (tid & 15) * 4;
    const int frag = row >> 4, r16 = row & 15;
    f32x4 s0 = *(const f32x4*)&part[frag][r16][col];
#pragma unroll
    for (int ww = 1; ww < 4; ++ww)
      s0 += *(const f32x4*)&part[frag + 2 * ww][r16][col];
    *(f32x4*)&logits[(size_t)(row0 + row) * E + col] = s0;
    *(f32x4*)&part[frag][r16][col] = s0;   // slabs 0..1 => contiguous [32][64]
  }
  __syncthreads();

  // --- fused top-2 + renorm: threads 0..31, one row each, staggered scan ---
  if (tid < 32) {
    const float* rowp = &part[0][0][0] + tid * 64;
    float bv = -3.4e38f; int bi = 1 << 30;
#pragma unroll 8
    for (int e0 = 0; e0 < E; ++e0) {
      const int e = (e0 + tid) & 63;   // stagger: conflict-free banks
      const float v = rowp[e];
      if (v > bv || (v == bv && e < bi)) { bv = v; bi = e; }
    }
    float sv = -3.4e38f; int si = 1 << 30;
#pragma unroll 8
    for (int e0 = 0; e0 < E; ++e0) {
      const int e = (e0 + tid) & 63;
      const float v = rowp[e];
      if (e != bi && (v > sv || (v == sv && e < si))) { sv = v; si = e; }
    }
    // w1 = p1/(p1+p2) = 1/(1+e^{x2-x1}); softmax denominator cancels
    const float w1 = 1.0f / (1.0f + __expf(sv - bv));
    const int R = row0 + tid;
    topw[(size_t)R * 2 + 0] = w1;
    topw[(size_t)R * 2 + 1] = 1.0f - w1;
    topi[(size_t)R * 2 + 0] = (float)bi;
    topi[(size_t)R * 2 + 1] = (float)si;
  }
}

extern "C" void kernel_launch(void* const* d_in, const int* in_sizes, int n_in,
                              void* d_out, int out_size, void* d_ws, size_t ws_size,
                              hipStream_t stream) {
  const float* H = (const float*)d_in[0];  // [16384, 4096] fp32
  const float* W = (const float*)d_in[1];  // [64, 4096] fp32

  float* out    = (float*)d_out;
  float* topw   = out;                       // [16384, 2]
  float* logits = out + (size_t)T * 2;       // [16384, 64]
  float* topi   = logits + (size_t)T * E;    // [16384, 2] (indices as float)

  short* wimg = (short*)d_ws;                // 1 MiB packed W image

  wprep<<<256, 256, 0, stream>>>(W, wimg);
  router_fused<<<T / 32, 512, 0, stream>>>(H, wimg, logits, topw, topi);
}